// Round 1
// baseline (200.407 us; speedup 1.0000x reference)
//
#include <hip/hip_runtime.h>

#define V 4096
#define F 64
#define H 16
#define GSZ 1024
#define EPS 1e-8f
#define SLOPE 0.2f

// ---------------- Kernel A: per-node precompute ----------------
__global__ __launch_bounds__(256) void prep_kernel(
    const float* __restrict__ feat,      // [V,F]
    const float* __restrict__ vel,       // [V,2]
    const int*   __restrict__ types,     // [V]
    const int*   __restrict__ nped,      // [1]
    const float* __restrict__ Wp,        // [F,H]
    const float* __restrict__ wscore,    // [2H+4]
    float* __restrict__ h,               // [V,H]
    float* __restrict__ li,              // [V]
    float* __restrict__ lj,              // [V]
    float* __restrict__ dir,             // [V,2]
    int*   __restrict__ gcflag)          // [V]
{
    int i = blockIdx.x * blockDim.x + threadIdx.x;
    if (i >= V) return;

    float acc[H];
#pragma unroll
    for (int c = 0; c < H; ++c) acc[c] = 0.f;
    for (int f = 0; f < F; ++f) {
        float x = feat[i * F + f];
#pragma unroll
        for (int c = 0; c < H; ++c) acc[c] += x * Wp[f * H + c];
    }
    float sli = 0.f, slj = 0.f;
#pragma unroll
    for (int c = 0; c < H; ++c) {
        h[i * H + c] = acc[c];
        sli += acc[c] * wscore[c];
        slj += acc[c] * wscore[H + c];
    }
    li[i] = sli;
    lj[i] = slj;

    float vx = vel[i * 2], vy = vel[i * 2 + 1];
    float sp = sqrtf(vx * vx + vy * vy);
    float inv = 1.f / (sp + EPS);
    dir[i * 2]     = vx * inv;
    dir[i * 2 + 1] = vy * inv;

    int P = nped[0];
    int g = i - P;
    gcflag[i] = (types[i] == 1 && g >= 0 && g < GSZ) ? g : -1;
}

// ---------------- Kernel B: one block per row ----------------
__global__ __launch_bounds__(256) void row_kernel(
    const float* __restrict__ adj,       // [V,V]
    const float* __restrict__ pos,       // [V,2]
    const float* __restrict__ vel,       // [V,2]
    const float* __restrict__ conflict,  // [G,G]
    const float* __restrict__ wscore,    // [2H+4]
    const float* __restrict__ h,         // [V,H]
    const float* __restrict__ li,        // [V]
    const float* __restrict__ lj,        // [V]
    const float* __restrict__ dir,       // [V,2]
    const int*   __restrict__ gcflag,    // [V]
    float* __restrict__ out_att,         // [V,H]
    float* __restrict__ out_attn,        // [V,V]
    float* __restrict__ out_phi)         // [V,V,4]
{
    const int i   = blockIdx.x;
    const int tid = threadIdx.x;

    __shared__ float zrow[V];   // logits -> exp values
    __shared__ float arow[V];   // adjacency row
    __shared__ float red[8];    // cross-wave scratch

    const float2* pos2 = reinterpret_cast<const float2*>(pos);
    const float2* vel2 = reinterpret_cast<const float2*>(vel);
    const float2* dir2 = reinterpret_cast<const float2*>(dir);

    const float2 pi = pos2[i];
    const float2 vi = vel2[i];
    const float2 di = dir2[i];
    const float  li_i = li[i];
    const int    gi   = gcflag[i];
    const float  w0 = wscore[2 * H + 0];
    const float  w1 = wscore[2 * H + 1];
    const float  w2 = wscore[2 * H + 2];
    const float  w3 = wscore[2 * H + 3];

    // ---- pass 1: phi + logits + row max ----
    float lmax = -3.4e38f;
    for (int j = tid; j < V; j += 256) {
        float a = adj[(size_t)i * V + j];
        float2 pj = pos2[j];
        float2 vj = vel2[j];
        float2 dj = dir2[j];
        float dx = pi.x - pj.x, dy = pi.y - pj.y;
        float dist = sqrtf(dx * dx + dy * dy);
        float dvx = vi.x - vj.x, dvy = vi.y - vj.y;
        float vdiff = sqrtf(dvx * dvx + dvy * dvy);
        float al = di.x * dj.x + di.y * dj.y;
        al = fminf(1.f, fmaxf(-1.f, al));
        int gj = gcflag[j];
        float conf = (gi >= 0 && gj >= 0) ? conflict[(size_t)gi * GSZ + gj] : 0.f;

        reinterpret_cast<float4*>(out_phi)[(size_t)i * V + j] =
            make_float4(dist, vdiff, al, conf);

        float lg = li_i + lj[j] + dist * w0 + vdiff * w1 + al * w2 + conf * w3;
        lg = (lg >= 0.f) ? lg : SLOPE * lg;
        float z = lg + ((a > 0.f) ? 0.f : -1e9f);
        zrow[j] = z;
        arow[j] = a;
        lmax = fmaxf(lmax, z);
    }
#pragma unroll
    for (int off = 32; off; off >>= 1) lmax = fmaxf(lmax, __shfl_xor(lmax, off));
    if ((tid & 63) == 0) red[tid >> 6] = lmax;
    __syncthreads();
    const float m = fmaxf(fmaxf(red[0], red[1]), fmaxf(red[2], red[3]));
    __syncthreads();  // protect red reuse

    // ---- pass 2: exp, s = sum e, t = sum e*adj ----
    float s = 0.f, t = 0.f;
    for (int j = tid; j < V; j += 256) {
        float e = expf(zrow[j] - m);
        zrow[j] = e;
        s += e;
        t += e * arow[j];
    }
#pragma unroll
    for (int off = 32; off; off >>= 1) {
        s += __shfl_xor(s, off);
        t += __shfl_xor(t, off);
    }
    if ((tid & 63) == 0) { red[tid >> 6] = s; red[4 + (tid >> 6)] = t; }
    __syncthreads();
    s = red[0] + red[1] + red[2] + red[3];
    t = red[4] + red[5] + red[6] + red[7];
    // attn = (e/s * a) / (sum(e/s * a) + EPS) == e*a / (t + EPS*s)
    const float dinv = 1.f / (t + EPS * s);

    // ---- pass 3: attn row + attended accumulation ----
    float acc[H];
#pragma unroll
    for (int c = 0; c < H; ++c) acc[c] = 0.f;
    const float4* h4 = reinterpret_cast<const float4*>(h);
    for (int j = tid; j < V; j += 256) {
        float w = zrow[j] * arow[j] * dinv;
        out_attn[(size_t)i * V + j] = w;
#pragma unroll
        for (int c4 = 0; c4 < H / 4; ++c4) {
            float4 hv = h4[j * (H / 4) + c4];
            acc[c4 * 4 + 0] += w * hv.x;
            acc[c4 * 4 + 1] += w * hv.y;
            acc[c4 * 4 + 2] += w * hv.z;
            acc[c4 * 4 + 3] += w * hv.w;
        }
    }
#pragma unroll
    for (int c = 0; c < H; ++c)
#pragma unroll
        for (int off = 32; off; off >>= 1) acc[c] += __shfl_xor(acc[c], off);

    __syncthreads();            // done reading zrow; reuse as reduce tile
    float* atile = zrow;
    if ((tid & 63) == 0) {
        int w = tid >> 6;
#pragma unroll
        for (int c = 0; c < H; ++c) atile[w * H + c] = acc[c];
    }
    __syncthreads();
    if (tid < H) {
        float sum = atile[tid] + atile[H + tid] + atile[2 * H + tid] + atile[3 * H + tid];
        out_att[(size_t)i * H + tid] = sum;
    }
}

extern "C" void kernel_launch(void* const* d_in, const int* in_sizes, int n_in,
                              void* d_out, int out_size, void* d_ws, size_t ws_size,
                              hipStream_t stream) {
    const float* feat     = (const float*)d_in[0];
    const float* adj      = (const float*)d_in[1];
    const float* pos      = (const float*)d_in[2];
    const float* vel      = (const float*)d_in[3];
    const int*   types    = (const int*)  d_in[4];
    const int*   nped     = (const int*)  d_in[5];
    const float* conflict = (const float*)d_in[6];
    const float* Wp       = (const float*)d_in[7];
    const float* wscore   = (const float*)d_in[8];

    float* out = (float*)d_out;
    float* out_att  = out;                         // [V,H]
    float* out_attn = out + (size_t)V * H;         // [V,V]
    float* out_phi  = out + (size_t)V * H + (size_t)V * V;  // [V,V,4]

    // workspace layout (floats)
    float* ws  = (float*)d_ws;
    float* h   = ws;                       // V*H
    float* li  = h  + (size_t)V * H;       // V
    float* lj  = li + V;                   // V
    float* dir = lj + V;                   // V*2
    int*   gcflag = (int*)(dir + (size_t)V * 2);   // V

    prep_kernel<<<dim3(V / 256), dim3(256), 0, stream>>>(
        feat, vel, types, nped, Wp, wscore, h, li, lj, dir, gcflag);

    row_kernel<<<dim3(V), dim3(256), 0, stream>>>(
        adj, pos, vel, conflict, wscore, h, li, lj, dir, gcflag,
        out_att, out_attn, out_phi);
}

// Round 2
// 157.808 us; speedup vs baseline: 1.2699x; 1.2699x over previous
//
#include <hip/hip_runtime.h>

#define V 4096
#define F 64
#define H 16
#define GSZ 1024
#define EPS 1e-8f
#define SLOPE 0.2f
#define NITER (V / 256)   // 16 columns per thread

typedef float f4 __attribute__((ext_vector_type(4)));

// ---------------- Kernel A: per-node precompute + packing ----------------
// nd[i*8 + 0..7] = {px, py, vx, vy, dirx, diry, lj, bitcast(gc)}
__global__ __launch_bounds__(256) void prep_kernel(
    const float* __restrict__ feat,      // [V,F]
    const float* __restrict__ pos,       // [V,2]
    const float* __restrict__ vel,       // [V,2]
    const int*   __restrict__ types,     // [V]
    const int*   __restrict__ nped,      // [1]
    const float* __restrict__ Wp,        // [F,H]
    const float* __restrict__ wscore,    // [2H+4]
    float* __restrict__ h,               // [V,H]
    float* __restrict__ li,              // [V]
    float* __restrict__ nd)              // [V,8]
{
    int i = blockIdx.x * blockDim.x + threadIdx.x;
    if (i >= V) return;

    float acc[H];
#pragma unroll
    for (int c = 0; c < H; ++c) acc[c] = 0.f;
    for (int f = 0; f < F; ++f) {
        float x = feat[i * F + f];
#pragma unroll
        for (int c = 0; c < H; ++c) acc[c] += x * Wp[f * H + c];
    }
    float sli = 0.f, slj = 0.f;
#pragma unroll
    for (int c = 0; c < H; ++c) {
        h[i * H + c] = acc[c];
        sli += acc[c] * wscore[c];
        slj += acc[c] * wscore[H + c];
    }
    li[i] = sli;

    float vx = vel[i * 2], vy = vel[i * 2 + 1];
    float inv = 1.f / (sqrtf(vx * vx + vy * vy) + EPS);
    int P = nped[0];
    int g = i - P;
    int gc = (types[i] == 1 && g >= 0 && g < GSZ) ? g : -1;

    nd[i * 8 + 0] = pos[i * 2];
    nd[i * 8 + 1] = pos[i * 2 + 1];
    nd[i * 8 + 2] = vx;
    nd[i * 8 + 3] = vy;
    nd[i * 8 + 4] = vx * inv;
    nd[i * 8 + 5] = vy * inv;
    nd[i * 8 + 6] = slj;
    nd[i * 8 + 7] = __int_as_float(gc);
}

// ---------------- Kernel B: one block per row, 2 passes, e in registers ----
__global__ __launch_bounds__(256, 4) void row_kernel(
    const float* __restrict__ adj,       // [V,V]
    const float* __restrict__ conflict,  // [G,G]
    const float* __restrict__ wscore,    // [2H+4]
    const float* __restrict__ h,         // [V,H]
    const float* __restrict__ li,        // [V]
    const float* __restrict__ nd,        // [V,8]
    float* __restrict__ out_att,         // [V,H]
    float* __restrict__ out_attn,        // [V,V]
    float* __restrict__ out_phi)         // [V,V,4]
{
    const int i   = blockIdx.x;
    const int tid = threadIdx.x;

    __shared__ float red[8];
    __shared__ float atile[4 * H];

    const f4* nd4 = (const f4*)nd;
    const f4 ra = nd4[2 * i];
    const f4 rb = nd4[2 * i + 1];
    const float pix = ra.x, piy = ra.y, vix = ra.z, viy = ra.w;
    const float dix = rb.x, diy = rb.y;
    const int   gi  = __float_as_int(rb.w);
    const float li_i = li[i];
    const float w0 = wscore[2 * H + 0];
    const float w1 = wscore[2 * H + 1];
    const float w2 = wscore[2 * H + 2];
    const float w3 = wscore[2 * H + 3];

    const float* adjrow  = adj + (size_t)i * V;
    f4*          phirow  = (f4*)out_phi + (size_t)i * V;
    float*       attnrow = out_attn + (size_t)i * V;

    // ---- pass 1: phi + e = exp(leaky(logit)) (max-shift-invariant), s, t ----
    float ereg[NITER];
    float s = 0.f, t = 0.f;
#pragma unroll
    for (int k = 0; k < NITER; ++k) {
        int j = tid + k * 256;
        float a = adjrow[j];
        f4 na = nd4[2 * j];
        f4 nb = nd4[2 * j + 1];
        float dx = pix - na.x, dy = piy - na.y;
        float dist = sqrtf(dx * dx + dy * dy);
        float dvx = vix - na.z, dvy = viy - na.w;
        float vdiff = sqrtf(dvx * dvx + dvy * dvy);
        float al = fminf(1.f, fmaxf(-1.f, dix * nb.x + diy * nb.y));
        int gj = __float_as_int(nb.w);
        float conf = (gi >= 0 && gj >= 0) ? conflict[(size_t)gi * GSZ + gj] : 0.f;

        f4 ph;
        ph.x = dist; ph.y = vdiff; ph.z = al; ph.w = conf;
        __builtin_nontemporal_store(ph, phirow + j);

        float lg = li_i + nb.z + dist * w0 + vdiff * w1 + al * w2 + conf * w3;
        lg = (lg >= 0.f) ? lg : SLOPE * lg;
        // suppressed entries: exp(lg - 1e9) == 0 exactly in fp32
        float e = (a > 0.f) ? __expf(fminf(lg, 80.f)) : 0.f;
        ereg[k] = e;
        s += e;
        t += e * a;
    }
#pragma unroll
    for (int off = 32; off; off >>= 1) {
        s += __shfl_xor(s, off);
        t += __shfl_xor(t, off);
    }
    if ((tid & 63) == 0) { red[tid >> 6] = s; red[4 + (tid >> 6)] = t; }
    __syncthreads();
    s = red[0] + red[1] + red[2] + red[3];
    t = red[4] + red[5] + red[6] + red[7];
    const float denom = t + EPS * s;
    const float dinv  = (denom > 0.f) ? 1.f / denom : 0.f;

    // ---- pass 2: attn row + attended accumulation ----
    float acc[H];
#pragma unroll
    for (int c = 0; c < H; ++c) acc[c] = 0.f;
    const f4* h4 = (const f4*)h;
#pragma unroll
    for (int k = 0; k < NITER; ++k) {
        int j = tid + k * 256;
        float a = adjrow[j];        // L2 hit (just read in pass 1)
        float w = ereg[k] * a * dinv;
        __builtin_nontemporal_store(w, attnrow + j);
#pragma unroll
        for (int c4 = 0; c4 < H / 4; ++c4) {
            f4 hv = h4[j * (H / 4) + c4];
            acc[c4 * 4 + 0] += w * hv.x;
            acc[c4 * 4 + 1] += w * hv.y;
            acc[c4 * 4 + 2] += w * hv.z;
            acc[c4 * 4 + 3] += w * hv.w;
        }
    }
#pragma unroll
    for (int c = 0; c < H; ++c)
#pragma unroll
        for (int off = 32; off; off >>= 1) acc[c] += __shfl_xor(acc[c], off);

    if ((tid & 63) == 0) {
        int wv = tid >> 6;
#pragma unroll
        for (int c = 0; c < H; ++c) atile[wv * H + c] = acc[c];
    }
    __syncthreads();
    if (tid < H) {
        out_att[(size_t)i * H + tid] =
            atile[tid] + atile[H + tid] + atile[2 * H + tid] + atile[3 * H + tid];
    }
}

extern "C" void kernel_launch(void* const* d_in, const int* in_sizes, int n_in,
                              void* d_out, int out_size, void* d_ws, size_t ws_size,
                              hipStream_t stream) {
    const float* feat     = (const float*)d_in[0];
    const float* adj      = (const float*)d_in[1];
    const float* pos      = (const float*)d_in[2];
    const float* vel      = (const float*)d_in[3];
    const int*   types    = (const int*)  d_in[4];
    const int*   nped     = (const int*)  d_in[5];
    const float* conflict = (const float*)d_in[6];
    const float* Wp       = (const float*)d_in[7];
    const float* wscore   = (const float*)d_in[8];

    float* out = (float*)d_out;
    float* out_att  = out;                                   // [V,H]
    float* out_attn = out + (size_t)V * H;                   // [V,V]
    float* out_phi  = out + (size_t)V * H + (size_t)V * V;   // [V,V,4]

    float* ws = (float*)d_ws;
    float* h  = ws;                        // V*H
    float* li = h + (size_t)V * H;         // V
    float* nd = li + V;                    // V*8

    prep_kernel<<<dim3(V / 256), dim3(256), 0, stream>>>(
        feat, pos, vel, types, nped, Wp, wscore, h, li, nd);

    row_kernel<<<dim3(V), dim3(256), 0, stream>>>(
        adj, conflict, wscore, h, li, nd, out_att, out_attn, out_phi);
}